// Round 5
// baseline (479.315 us; speedup 1.0000x reference)
//
#include <hip/hip_runtime.h>
#include <hip/hip_bf16.h>
#include <stdint.h>

#define IN_F 2048
#define OUT_F 8192
#define NROWS 2048
#define NS 32

typedef float  vf4  __attribute__((ext_vector_type(4)));
typedef short  vs8  __attribute__((ext_vector_type(8)));
typedef float  vacc __attribute__((ext_vector_type(4)));
typedef unsigned int vu4 __attribute__((ext_vector_type(4)));

__device__ __forceinline__ short f2bf(float f) {
    return __builtin_bit_cast(short, __float2bfloat16(f));
}

__device__ __forceinline__ void gl2lds16(const void* g, void* l) {
    __builtin_amdgcn_global_load_lds((__attribute__((address_space(1))) void*)g,
                                     (__attribute__((address_space(3))) void*)l,
                                     16, 0, 0);
}

// K0: thr[r][i] = thresholds[r][i] * std[i]
__global__ void __launch_bounds__(256) k_thr(const float* __restrict__ thresholds,
                                             const float* __restrict__ stdv,
                                             float* __restrict__ thr) {
    int idx = (blockIdx.x * 256 + threadIdx.x) * 4;
    vf4 t = *(const vf4*)(thresholds + idx);
    vf4 s = *(const vf4*)(stdv + (idx & (IN_F - 1)));
    *(vf4*)(thr + idx) = t * s;
}

// K1: Wt[o][k] bf16, row = 4096B, k-tile t=k/64 at bytes [t*128,+128),
// within tile byte = (2*(k%64)) ^ ((o&7)<<4)   (pre-swizzled for K2)
__global__ void __launch_bounds__(256) k_wt(const float* __restrict__ W,
                                            char* __restrict__ Wt) {
    __shared__ float tile[64 * 64];
    int kt = blockIdx.x & 31;   // 32 k-tiles
    int ot = blockIdx.x >> 5;   // 128 o-tiles
    int t = threadIdx.x;
    int kbase = kt * 64, obase = ot * 64;
#pragma unroll
    for (int rr = 0; rr < 4; ++rr) {
        int r = rr * 16 + (t >> 4);
        int c = (t & 15) * 4;
        vf4 v = *(const vf4*)(W + (size_t)(kbase + r) * OUT_F + obase + c);
        *(vf4*)(tile + r * 64 + c) = v;
    }
    __syncthreads();
    int o = t & 63;
    int kc = (t >> 6) * 16;     // 16 k per thread
    int og = obase + o;
    unsigned int pk[8];
#pragma unroll
    for (int j = 0; j < 8; ++j) {
        unsigned short lo = (unsigned short)f2bf(tile[(kc + 2 * j) * 64 + o]);
        unsigned short hi = (unsigned short)f2bf(tile[(kc + 2 * j + 1) * 64 + o]);
        pk[j] = (unsigned int)lo | ((unsigned int)hi << 16);
    }
    int s = (og & 7) << 4;
    char* rowp = Wt + (size_t)og * 4096 + kt * 128;
    vu4 a = {pk[0], pk[1], pk[2], pk[3]};
    vu4 b = {pk[4], pk[5], pk[6], pk[7]};
    *(vu4*)(rowp + (((kc * 2) + 0) ^ s)) = a;
    *(vu4*)(rowp + (((kc * 2) + 16) ^ s)) = b;
}

// K2: per-stripe masked GEMM. 128x128 tile, BK=64, 4 waves (wave-tile 64x64).
__global__ void __launch_bounds__(256) k_gemm(const float* __restrict__ x,
                                              const char* __restrict__ Wt,
                                              const float* __restrict__ bias,
                                              const float* __restrict__ mu,
                                              const float* __restrict__ thr,
                                              float* __restrict__ y) {
    __shared__ char lds[32768];   // A: [0,16K) 128 rows x 128B ; B: [16K,32K)

    int bid = blockIdx.x;
    int swz = (bid & 7) * 128 + (bid >> 3);   // XCD swizzle, 1024 % 8 == 0
    int mt = swz & 15, nt = swz >> 4;
    int m_base = mt * 128, n_base = nt * 128;
    const float* thrR = thr + (size_t)(nt >> 1) * IN_F;   // stripe

    int t = threadIdx.x;
    int w = t >> 6, lane = t & 63;
    int lane16 = lane & 15, g = lane >> 4;
    int wm = w >> 1, wn = w & 1;

    // A staging mapping: 2 threads per row, 32 k each
    int am = t >> 1;
    int ah = (t & 1) * 32;
    const float* xrow = x + (size_t)(m_base + am) * IN_F;
    int sA = (am & 7) << 4;
    char* arow = lds + am * 128;

    // B staging mapping
    int brow = lane >> 3;
    int bcol = (lane & 7) * 16;

    vacc acc[4][4];
#pragma unroll
    for (int i = 0; i < 4; ++i)
#pragma unroll
        for (int j = 0; j < 4; ++j)
            acc[i][j] = (vacc){0.f, 0.f, 0.f, 0.f};

    for (int kt = 0; kt < IN_F / 64; ++kt) {
        // ---- stage B: Wt -> LDS, linear, pre-swizzled
#pragma unroll
        for (int q = 0; q < 4; ++q) {
            int row = (w * 4 + q) * 8 + brow;   // 0..127
            const char* src = Wt + (size_t)(n_base + row) * 4096 + kt * 128 + bcol;
            gl2lds16(src, lds + 16384 + (w * 4 + q) * 1024);
        }
        // ---- stage A: load x, fused mask transform, bf16, swizzled write
        const float* xp = xrow + kt * 64 + ah;
        const float* mp = mu + kt * 64 + ah;
        const float* tp = thrR + kt * 64 + ah;
#pragma unroll
        for (int v = 0; v < 4; ++v) {
            vf4 x0 = *(const vf4*)(xp + v * 8);
            vf4 x1 = *(const vf4*)(xp + v * 8 + 4);
            vf4 m0 = *(const vf4*)(mp + v * 8);
            vf4 m1 = *(const vf4*)(mp + v * 8 + 4);
            vf4 t0 = *(const vf4*)(tp + v * 8);
            vf4 t1 = *(const vf4*)(tp + v * 8 + 4);
            vs8 o;
#pragma unroll
            for (int j = 0; j < 4; ++j) {
                float xm = x0[j] - m0[j];
                float sel = (__builtin_fabsf(xm) > t0[j]) ? x0[j] : m0[j];
                o[j] = f2bf(sel);
            }
#pragma unroll
            for (int j = 0; j < 4; ++j) {
                float xm = x1[j] - m1[j];
                float sel = (__builtin_fabsf(xm) > t1[j]) ? x1[j] : m1[j];
                o[4 + j] = f2bf(sel);
            }
            *(vs8*)(arow + ((ah * 2 + v * 16) ^ sA)) = o;
        }
        __syncthreads();
        // ---- compute
#pragma unroll
        for (int ks = 0; ks < 2; ++ks) {
            vs8 af[4], bf[4];
#pragma unroll
            for (int i = 0; i < 4; ++i) {
                int row = wm * 64 + i * 16 + lane16;
                af[i] = *(const vs8*)(lds + row * 128 +
                                      ((ks * 64 + g * 16) ^ ((row & 7) << 4)));
                int col = wn * 64 + i * 16 + lane16;
                bf[i] = *(const vs8*)(lds + 16384 + col * 128 +
                                      ((ks * 64 + g * 16) ^ ((col & 7) << 4)));
            }
#pragma unroll
            for (int i = 0; i < 4; ++i)
#pragma unroll
                for (int j = 0; j < 4; ++j)
                    acc[i][j] = __builtin_amdgcn_mfma_f32_16x16x32_bf16(
                        af[i], bf[j], acc[i][j], 0, 0, 0);
        }
        __syncthreads();
    }

    // ---- epilogue: + bias, coalesced-ish scalar stores
    float* yb = y + (size_t)(m_base + wm * 64) * OUT_F + n_base + wn * 64;
#pragma unroll
    for (int j = 0; j < 4; ++j) {
        int ng = j * 16 + lane16;
        float bv = bias[n_base + wn * 64 + ng];
#pragma unroll
        for (int i = 0; i < 4; ++i) {
            int mg = i * 16 + g * 4;
#pragma unroll
            for (int q = 0; q < 4; ++q)
                yb[(size_t)(mg + q) * OUT_F + ng] = acc[i][j][q] + bv;
        }
    }
}

// K3: dense fill + exact mask count -> sparse_flops. 8 rows per block.
__global__ void __launch_bounds__(256) k_aux(const float* __restrict__ x,
                                             const float* __restrict__ mu,
                                             const float* __restrict__ thr,
                                             float* __restrict__ dense,
                                             float* __restrict__ sparse) {
    __shared__ int cnt[8];
    int t = threadIdx.x;
    if (t < 8) cnt[t] = 0;
    __syncthreads();
    int rb = blockIdx.x * 8;
    int i8 = t * 8;
    vf4 m0 = *(const vf4*)(mu + i8);
    vf4 m1 = *(const vf4*)(mu + i8 + 4);
#pragma unroll
    for (int pass = 0; pass < 2; ++pass) {
        float ax[4][8];
#pragma unroll
        for (int rr = 0; rr < 4; ++rr) {
            int row = rb + pass * 4 + rr;
            vf4 x0 = *(const vf4*)(x + (size_t)row * IN_F + i8);
            vf4 x1 = *(const vf4*)(x + (size_t)row * IN_F + i8 + 4);
#pragma unroll
            for (int j = 0; j < 4; ++j) {
                ax[rr][j] = __builtin_fabsf(x0[j] - m0[j]);
                ax[rr][4 + j] = __builtin_fabsf(x1[j] - m1[j]);
            }
        }
        int c[4] = {0, 0, 0, 0};
        for (int r = 0; r < NS; ++r) {
            vf4 t0 = *(const vf4*)(thr + (size_t)r * IN_F + i8);
            vf4 t1 = *(const vf4*)(thr + (size_t)r * IN_F + i8 + 4);
#pragma unroll
            for (int rr = 0; rr < 4; ++rr) {
#pragma unroll
                for (int j = 0; j < 4; ++j) {
                    c[rr] += (ax[rr][j] > t0[j]) ? 1 : 0;
                    c[rr] += (ax[rr][4 + j] > t1[j]) ? 1 : 0;
                }
            }
        }
#pragma unroll
        for (int rr = 0; rr < 4; ++rr) atomicAdd(&cnt[pass * 4 + rr], c[rr]);
    }
    __syncthreads();
    if (t < 8) {
        dense[rb + t] = 16777216.0f;
        sparse[rb + t] = 256.0f * (float)cnt[t];
    }
}

extern "C" void kernel_launch(void* const* d_in, const int* in_sizes, int n_in,
                              void* d_out, int out_size, void* d_ws, size_t ws_size,
                              hipStream_t stream) {
    const float* x = (const float*)d_in[0];
    const float* W = (const float*)d_in[1];
    const float* bias = (const float*)d_in[2];
    const float* mu = (const float*)d_in[3];
    const float* stdv = (const float*)d_in[4];
    const float* thresholds = (const float*)d_in[5];

    float* y = (float*)d_out;
    float* dense = y + (size_t)NROWS * OUT_F;
    float* sparse = dense + NROWS;

    char* Wt = (char*)d_ws;                                   // 32 MiB bf16, swizzled
    float* thr = (float*)(Wt + (size_t)OUT_F * IN_F * 2);     // 256 KiB

    hipLaunchKernelGGL(k_thr, dim3((NS * IN_F) / 1024), dim3(256), 0, stream,
                       thresholds, stdv, thr);
    hipLaunchKernelGGL(k_wt, dim3((IN_F / 64) * (OUT_F / 64)), dim3(256), 0, stream,
                       W, Wt);
    hipLaunchKernelGGL(k_gemm, dim3((NROWS / 128) * (OUT_F / 128)), dim3(256), 0,
                       stream, x, Wt, bias, mu, thr, y);
    hipLaunchKernelGGL(k_aux, dim3(NROWS / 8), dim3(256), 0, stream,
                       x, mu, thr, dense, sparse);
}

// Round 6
// 313.765 us; speedup vs baseline: 1.5276x; 1.5276x over previous
//
#include <hip/hip_runtime.h>
#include <hip/hip_bf16.h>
#include <stdint.h>

#define IN_F 2048
#define OUT_F 8192
#define NROWS 2048
#define NS 32

typedef float  vf4  __attribute__((ext_vector_type(4)));
typedef short  vs8  __attribute__((ext_vector_type(8)));
typedef float  vacc __attribute__((ext_vector_type(4)));
typedef unsigned int vu4 __attribute__((ext_vector_type(4)));

__device__ __forceinline__ short f2bf(float f) {
    return __builtin_bit_cast(short, __float2bfloat16(f));
}

__device__ __forceinline__ void gl2lds16(const void* g, void* l) {
    __builtin_amdgcn_global_load_lds((__attribute__((address_space(1))) void*)g,
                                     (__attribute__((address_space(3))) void*)l,
                                     16, 0, 0);
}

// K0: thr = thresholds*std  (+ dense_flops constant fill)
__global__ void __launch_bounds__(256) k_thr(const float* __restrict__ thresholds,
                                             const float* __restrict__ stdv,
                                             float* __restrict__ thr,
                                             float* __restrict__ dense) {
    int gid = blockIdx.x * 256 + threadIdx.x;
    int idx = gid * 4;
    vf4 t = *(const vf4*)(thresholds + idx);
    vf4 s = *(const vf4*)(stdv + (idx & (IN_F - 1)));
    *(vf4*)(thr + idx) = t * s;
    if (gid < NROWS / 4) {
        vf4 d = {16777216.0f, 16777216.0f, 16777216.0f, 16777216.0f};
        *(vf4*)(dense + gid * 4) = d;
    }
}

// K1: W[k][o] f32 -> Wt[o][k] bf16, pre-swizzled (byte ^ (o&7)<<4 per 128B k-tile).
// Coalesced stores via stride-33-uint LDS repack (<=2-way banks both phases).
__global__ void __launch_bounds__(256) k_wt(const float* __restrict__ W,
                                            char* __restrict__ Wt) {
    __shared__ float tile[64 * 64];          // [k][o] f32
    __shared__ unsigned int tbf[64 * 33];    // [o][k-pair], stride 33 uints = 132B
    int kt = blockIdx.x & 31;
    int ot = blockIdx.x >> 5;
    int t = threadIdx.x;
    int kbase = kt * 64, obase = ot * 64;
#pragma unroll
    for (int rr = 0; rr < 4; ++rr) {
        int r = rr * 16 + (t >> 4);
        int c = (t & 15) * 4;
        *(vf4*)(tile + r * 64 + c) =
            *(const vf4*)(W + (size_t)(kbase + r) * OUT_F + obase + c);
    }
    __syncthreads();
    int o = t & 63;
    int kc2 = (t >> 6) * 8;   // uint index base (k-pair), covers k = kc2*2 .. +15
#pragma unroll
    for (int j = 0; j < 8; ++j) {
        unsigned short lo = (unsigned short)f2bf(tile[(kc2 * 2 + 2 * j) * 64 + o]);
        unsigned short hi = (unsigned short)f2bf(tile[(kc2 * 2 + 2 * j + 1) * 64 + o]);
        tbf[o * 33 + kc2 + j] = (unsigned)lo | ((unsigned)hi << 16);
    }
    __syncthreads();
    int r = t >> 2, seg = t & 3;   // 4 threads cover one 128B row-segment
    unsigned int d[8];
#pragma unroll
    for (int i = 0; i < 8; ++i) d[i] = tbf[r * 33 + seg * 8 + i];
    int s = (r & 7) << 4;
    char* rowp = Wt + (size_t)(obase + r) * 4096 + kt * 128;
    vu4 a = {d[0], d[1], d[2], d[3]};
    vu4 b = {d[4], d[5], d[6], d[7]};
    *(vu4*)(rowp + ((seg * 32) ^ s)) = a;
    *(vu4*)(rowp + ((seg * 32 + 16) ^ s)) = b;
}

// K2: pipelined per-stripe masked GEMM, 128x128 tile, BK=64, 4 waves.
// LDS: A 16K | B dbuf 2x16K | mu 8K | thr 8K = 64KB. Fused sparse-count.
#define LDS_A  0
#define LDS_B  16384
#define LDS_MU 49152
#define LDS_TH 57344

struct XR { vf4 a[8]; };

__global__ void __launch_bounds__(256, 2) k_gemm(const float* __restrict__ x,
                                                 const char* __restrict__ Wt,
                                                 const float* __restrict__ bias,
                                                 const float* __restrict__ mu,
                                                 const float* __restrict__ thr,
                                                 float* __restrict__ y,
                                                 float* __restrict__ sparse) {
    __shared__ char lds[65536];

    int bid = blockIdx.x;
    int swz = (bid & 7) * 128 + (bid >> 3);   // XCD-contiguous, bijective (1024%8==0)
    int mt = swz >> 6, nt = swz & 63;         // mt-major per XCD: x stays L2-hot
    int m_base = mt * 128, n_base = nt * 128;
    const float* thrR = thr + (size_t)(nt >> 1) * IN_F;

    int t = threadIdx.x;
    int w = t >> 6, lane = t & 63;
    int lane16 = lane & 15, g = lane >> 4;
    int wm = w >> 1, wn = w & 1;

    int am = t >> 1;
    int ah = (t & 1) * 32;
    const float* xrow = x + (size_t)(m_base + am) * IN_F + ah;
    int sA = (am & 7) << 4;
    char* arow = lds + LDS_A + am * 128;

    int brow = lane >> 3;
    int bcol = (lane & 7) * 16;

    // ---- prologue: mu + thr stripe -> LDS (once), drained before anything else
    {
        const char* mug = (const char*)mu;
        const char* thg = (const char*)thrR;
#pragma unroll
        for (int p = 0; p < 2; ++p) {
            gl2lds16(mug + p * 4096 + w * 1024 + lane * 16,
                     lds + LDS_MU + p * 4096 + w * 1024);
            gl2lds16(thg + p * 4096 + w * 1024 + lane * 16,
                     lds + LDS_TH + p * 4096 + w * 1024);
        }
        asm volatile("s_waitcnt vmcnt(0)" ::: "memory");
    }

    auto stageB = [&](int kt, int buf) {
#pragma unroll
        for (int q = 0; q < 4; ++q) {
            const char* src = Wt + (size_t)(n_base + (w * 4 + q) * 8 + brow) * 4096 +
                              kt * 128 + bcol;
            gl2lds16(src, lds + LDS_B + buf * 16384 + (w * 4 + q) * 1024);
        }
    };
    auto load_x = [&](int kt, XR& r) {
        const float* p = xrow + kt * 64;
#pragma unroll
        for (int v = 0; v < 8; ++v) r.a[v] = *(const vf4*)(p + v * 4);
    };

    vacc acc[4][4];
#pragma unroll
    for (int i = 0; i < 4; ++i)
#pragma unroll
        for (int j = 0; j < 4; ++j)
            acc[i][j] = (vacc){0.f, 0.f, 0.f, 0.f};
    int cnt = 0;

    XR xa, xb;
    stageB(0, 0);
    load_x(0, xa);

    auto xform = [&](XR& r, int kt) {
        const char* muL = lds + LDS_MU + kt * 256 + ah * 4;
        const char* thL = lds + LDS_TH + kt * 256 + ah * 4;
#pragma unroll
        for (int v = 0; v < 4; ++v) {
            vf4 x0 = r.a[2 * v], x1 = r.a[2 * v + 1];
            vf4 m0 = *(const vf4*)(muL + v * 32);
            vf4 m1 = *(const vf4*)(muL + v * 32 + 16);
            vf4 t0 = *(const vf4*)(thL + v * 32);
            vf4 t1 = *(const vf4*)(thL + v * 32 + 16);
            vs8 o;
#pragma unroll
            for (int j = 0; j < 4; ++j) {
                float xm = x0[j] - m0[j];
                bool m = __builtin_fabsf(xm) > t0[j];
                cnt += m ? 1 : 0;
                o[j] = f2bf(m ? x0[j] : m0[j]);
            }
#pragma unroll
            for (int j = 0; j < 4; ++j) {
                float xm = x1[j] - m1[j];
                bool m = __builtin_fabsf(xm) > t1[j];
                cnt += m ? 1 : 0;
                o[4 + j] = f2bf(m ? x1[j] : m1[j]);
            }
            *(vs8*)(arow + ((ah * 2 + v * 16) ^ sA)) = o;
        }
    };

    auto compute = [&](int buf) {
        const char* bbase = lds + LDS_B + buf * 16384;
#pragma unroll
        for (int ks = 0; ks < 2; ++ks) {
            vs8 af[4], bf[4];
#pragma unroll
            for (int i = 0; i < 4; ++i) {
                int row = wm * 64 + i * 16 + lane16;
                af[i] = *(const vs8*)(lds + LDS_A + row * 128 +
                                      ((ks * 64 + g * 16) ^ ((row & 7) << 4)));
                int col = wn * 64 + i * 16 + lane16;
                bf[i] = *(const vs8*)(bbase + col * 128 +
                                      ((ks * 64 + g * 16) ^ ((col & 7) << 4)));
            }
#pragma unroll
            for (int i = 0; i < 4; ++i)
#pragma unroll
                for (int j = 0; j < 4; ++j)
                    acc[i][j] = __builtin_amdgcn_mfma_f32_16x16x32_bf16(
                        af[i], bf[j], acc[i][j], 0, 0, 0);
        }
    };

    auto step = [&](int kt, XR& cur, XR& nxt) {
        bool pre = kt < 31;
        if (pre) load_x(kt + 1, nxt);          // x(t+1) -> regs, latency spans iter
        __builtin_amdgcn_sched_barrier(0);
        __builtin_amdgcn_s_barrier();          // #1: all waves done reading ldsA/ldsB[cur^1]
        __builtin_amdgcn_sched_barrier(0);
        if (pre) stageB(kt + 1, (kt + 1) & 1); // B(t+1) -> other buffer, stays in flight
        xform(cur, kt);                        // transform + count + ds_write A
        if (pre) asm volatile("s_waitcnt vmcnt(12)" ::: "memory");  // B(t) landed
        else     asm volatile("s_waitcnt vmcnt(0)" ::: "memory");
        asm volatile("s_waitcnt lgkmcnt(0)" ::: "memory");          // A writes visible
        __builtin_amdgcn_s_barrier();          // #2: tile ready
        __builtin_amdgcn_sched_barrier(0);
        compute(kt & 1);
    };

    for (int kt = 0; kt < 32; kt += 2) {
        step(kt, xa, xb);
        step(kt + 1, xb, xa);
    }

    // ---- epilogue: + bias
    float* yb = y + (size_t)(m_base + wm * 64) * OUT_F + n_base + wn * 64;
#pragma unroll
    for (int j = 0; j < 4; ++j) {
        int ng = j * 16 + lane16;
        float bv = bias[n_base + wn * 64 + ng];
#pragma unroll
        for (int i = 0; i < 4; ++i) {
            int mg = i * 16 + g * 4;
#pragma unroll
            for (int q = 0; q < 4; ++q)
                yb[(size_t)(mg + q) * OUT_F + ng] = acc[i][j][q] + bv;
        }
    }

    // ---- fused sparse_flops: one block per (m-tile, stripe) counts (nt even).
    // All partials are multiples of 256 <= 2^24 -> f32 atomicAdd exact.
    if ((nt & 1) == 0)
        atomicAdd(sparse + m_base + am, 256.0f * (float)cnt);
}

extern "C" void kernel_launch(void* const* d_in, const int* in_sizes, int n_in,
                              void* d_out, int out_size, void* d_ws, size_t ws_size,
                              hipStream_t stream) {
    const float* x = (const float*)d_in[0];
    const float* W = (const float*)d_in[1];
    const float* bias = (const float*)d_in[2];
    const float* mu = (const float*)d_in[3];
    const float* stdv = (const float*)d_in[4];
    const float* thresholds = (const float*)d_in[5];

    float* y = (float*)d_out;
    float* dense = y + (size_t)NROWS * OUT_F;
    float* sparse = dense + NROWS;

    char* Wt = (char*)d_ws;                                   // 32 MiB bf16, swizzled
    float* thr = (float*)(Wt + (size_t)OUT_F * IN_F * 2);     // 256 KiB

    hipLaunchKernelGGL(k_thr, dim3((NS * IN_F) / 1024), dim3(256), 0, stream,
                       thresholds, stdv, thr, dense);
    hipLaunchKernelGGL(k_wt, dim3((IN_F / 64) * (OUT_F / 64)), dim3(256), 0, stream,
                       W, Wt);
    hipMemsetAsync(sparse, 0, NROWS * sizeof(float), stream);
    hipLaunchKernelGGL(k_gemm, dim3((NROWS / 128) * (OUT_F / 128)), dim3(256), 0,
                       stream, x, Wt, bias, mu, thr, y, sparse);
}